// Round 1
// baseline (562.239 us; speedup 1.0000x reference)
//
#include <hip/hip_runtime.h>
#include <cstdint>

typedef __attribute__((ext_vector_type(8))) __bf16 bf16_8;
typedef __attribute__((ext_vector_type(4))) float f32x4;

// ---------------------------------------------------------------------------
// async global->LDS, 16B per lane. LDS dest = wave-uniform base + lane*16.
// ---------------------------------------------------------------------------
__device__ __forceinline__ void gld_lds16(const __bf16* g, __bf16* l) {
  __builtin_amdgcn_global_load_lds(
      (const __attribute__((address_space(1))) void*)(void*)g,
      (__attribute__((address_space(3))) void*)l, 16, 0, 0);
}

// ---------------------------------------------------------------------------
// Fused weight transpose + f32->bf16 convert.  W[K][N] -> Wt[N][K] bf16.
// 32x32 tiles; Wq/Wk/Wv/Wp: 1024 tiles each; W1,W2: 4096 tiles each.
// ---------------------------------------------------------------------------
__global__ __launch_bounds__(256) void convt_k(
    const float* __restrict__ Wq, const float* __restrict__ Wk,
    const float* __restrict__ Wv, const float* __restrict__ Wp,
    const float* __restrict__ W1, const float* __restrict__ W2,
    __bf16* __restrict__ WqT, __bf16* __restrict__ WkT,
    __bf16* __restrict__ WvT, __bf16* __restrict__ WpT,
    __bf16* __restrict__ W1T, __bf16* __restrict__ W2T) {
  int bid = blockIdx.x;
  const float* in; __bf16* outp; int Kd, Nd, tile;
  if (bid < 4096) {
    int m = bid >> 10; tile = bid & 1023; Kd = 1024; Nd = 1024;
    in   = m == 0 ? Wq  : m == 1 ? Wk  : m == 2 ? Wv  : Wp;
    outp = m == 0 ? WqT : m == 1 ? WkT : m == 2 ? WvT : WpT;
  } else if (bid < 8192) {
    tile = bid - 4096; Kd = 1024; Nd = 4096; in = W1; outp = W1T;
  } else {
    tile = bid - 8192; Kd = 4096; Nd = 1024; in = W2; outp = W2T;
  }
  int tilesN = Nd >> 5;
  int tk = tile / tilesN, tn = tile % tilesN;
  int k0 = tk * 32, n0 = tn * 32;
  __shared__ float tbuf[32][33];
  int tx = threadIdx.x & 31, ty = threadIdx.x >> 5;  // ty 0..7
#pragma unroll
  for (int i = 0; i < 4; ++i)
    tbuf[ty + i * 8][tx] = in[(size_t)(k0 + ty + i * 8) * Nd + (n0 + tx)];
  __syncthreads();
#pragma unroll
  for (int i = 0; i < 4; ++i)
    outp[(size_t)(n0 + ty + i * 8) * Kd + (k0 + tx)] = (__bf16)tbuf[tx][ty + i * 8];
}

// ---------------------------------------------------------------------------
// LayerNorm over rows of 1024, fp32 in -> bf16 out.  One block per row.
// ---------------------------------------------------------------------------
__global__ __launch_bounds__(256) void ln_k(const float* __restrict__ x,
                                            const float* __restrict__ w,
                                            const float* __restrict__ b,
                                            __bf16* __restrict__ out) {
  int row = blockIdx.x;
  const float* xr = x + (size_t)row * 1024;
  int tid = threadIdx.x;
  float v[4]; float s = 0.f, sq = 0.f;
#pragma unroll
  for (int i = 0; i < 4; ++i) {
    v[i] = xr[tid + i * 256]; s += v[i]; sq += v[i] * v[i];
  }
#pragma unroll
  for (int m = 1; m < 64; m <<= 1) { s += __shfl_xor(s, m); sq += __shfl_xor(sq, m); }
  __shared__ float rs[4], rq[4];
  int wave = tid >> 6, lane = tid & 63;
  if (lane == 0) { rs[wave] = s; rq[wave] = sq; }
  __syncthreads();
  s  = rs[0] + rs[1] + rs[2] + rs[3];
  sq = rq[0] + rq[1] + rq[2] + rq[3];
  float mu   = s * (1.f / 1024.f);
  float var  = sq * (1.f / 1024.f) - mu * mu;
  float rstd = rsqrtf(var + 1e-5f);
  __bf16* orow = out + (size_t)row * 1024;
#pragma unroll
  for (int i = 0; i < 4; ++i) {
    int c = tid + i * 256;
    orow[c] = (__bf16)((v[i] - mu) * rstd * w[c] + b[c]);
  }
}

// ---------------------------------------------------------------------------
// m97-style bf16 GEMM: C[M][N] = A[M][K] @ B[K][N], B given transposed
// Bt[N][K].  128x128 tile, BK=32, 4 waves each 64x64 (4x4 of 16x16x32 MFMA).
// MODE 0: bf16 out (per-chunk, fused QKV via blockIdx.y)
// MODE 1: bf16 out, +bias, ReLU
// MODE 2: f32  out, +bias, +f32 residual
// ---------------------------------------------------------------------------
template <int MODE>
__global__ __launch_bounds__(256) void gemm_k(
    const __bf16* __restrict__ A,
    const __bf16* __restrict__ B0, const __bf16* __restrict__ B1,
    const __bf16* __restrict__ B2,
    __bf16* __restrict__ O0, __bf16* __restrict__ O1, __bf16* __restrict__ O2,
    float* __restrict__ Of,
    const float* __restrict__ bias, const float* __restrict__ res,
    int K, int Nchunk, int nBlkN) {
  __shared__ __align__(16) __bf16 As[128 * 32];
  __shared__ __align__(16) __bf16 Bs[128 * 32];
  int chunk = blockIdx.y;
  const __bf16* Bt = chunk == 0 ? B0 : (chunk == 1 ? B1 : B2);
  __bf16* Ob       = chunk == 0 ? O0 : (chunk == 1 ? O1 : O2);
  int bm = blockIdx.x / nBlkN, bn = blockIdx.x % nBlkN;
  int m0 = bm * 128, n0 = bn * 128;
  int tid = threadIdx.x, wave = tid >> 6, lane = tid & 63;
  int quad = lane >> 4, l16 = lane & 15;
  int wm = (wave & 1) * 64, wn = (wave >> 1) * 64;

  f32x4 z = {0.f, 0.f, 0.f, 0.f};
  f32x4 acc[4][4];
#pragma unroll
  for (int mt = 0; mt < 4; ++mt)
#pragma unroll
    for (int nt = 0; nt < 4; ++nt) acc[mt][nt] = z;

  const __bf16* Ag = A  + (size_t)m0 * K;
  const __bf16* Bg = Bt + (size_t)n0 * K;
  int srow = lane >> 2;        // 16 rows per 1KB instruction
  int scol = (lane & 3) * 8;   // element offset within row

  for (int k0 = 0; k0 < K; k0 += 32) {
#pragma unroll
    for (int i = 0; i < 2; ++i) {
      int row = i * 64 + wave * 16 + srow;
      gld_lds16(Ag + (size_t)row * K + k0 + scol, As + (i * 64 + wave * 16) * 32);
      gld_lds16(Bg + (size_t)row * K + k0 + scol, Bs + (i * 64 + wave * 16) * 32);
    }
    __syncthreads();
    bf16_8 af[4], bfr[4];
#pragma unroll
    for (int t = 0; t < 4; ++t) {
      af[t]  = *(const bf16_8*)(As + (wm + t * 16 + l16) * 32 + quad * 8);
      bfr[t] = *(const bf16_8*)(Bs + (wn + t * 16 + l16) * 32 + quad * 8);
    }
#pragma unroll
    for (int mt = 0; mt < 4; ++mt)
#pragma unroll
      for (int nt = 0; nt < 4; ++nt)
        acc[mt][nt] = __builtin_amdgcn_mfma_f32_16x16x32_bf16(af[mt], bfr[nt],
                                                              acc[mt][nt], 0, 0, 0);
    __syncthreads();
  }

#pragma unroll
  for (int mt = 0; mt < 4; ++mt) {
#pragma unroll
    for (int r = 0; r < 4; ++r) {
      int m = m0 + wm + mt * 16 + quad * 4 + r;
      size_t rowo = (size_t)m * Nchunk;
#pragma unroll
      for (int nt = 0; nt < 4; ++nt) {
        int n = n0 + wn + nt * 16 + l16;
        float v = acc[mt][nt][r];
        if (MODE == 0) {
          Ob[rowo + n] = (__bf16)v;
        } else if (MODE == 1) {
          v += bias[n]; v = v > 0.f ? v : 0.f;
          Ob[rowo + n] = (__bf16)v;
        } else {
          v += bias[n] + res[rowo + n];
          Of[rowo + n] = v;
        }
      }
    }
  }
}

// ---------------------------------------------------------------------------
// Flash attention, causal.  One workgroup = (b,h, 64 q-rows); one wave = 16
// q-rows.  Key tiles of 32.  K staged [key][d] (B-layout for QK^T), V staged
// transposed [d][key] (B-layout for PV), P goes C-layout -> LDS -> A-layout.
// scale = C^-0.5 = 1/32 (reference scales by n_embd, not head_size).
// ---------------------------------------------------------------------------
__global__ __launch_bounds__(256) void attn_k(const __bf16* __restrict__ Q,
                                              const __bf16* __restrict__ K,
                                              const __bf16* __restrict__ V,
                                              __bf16* __restrict__ O) {
  __shared__ __align__(16) __bf16 Kls[32 * 64];     // [key][d]
  __shared__ __align__(16) __bf16 Vls[64 * 32];     // [d][key]
  __shared__ __align__(16) __bf16 Pls[4][16 * 32];  // per-wave [m][key]

  int blk = blockIdx.x;
  int qt = blk & 31;        // T/64 = 32 q-tiles
  int bh = blk >> 5;
  int h = bh & 15, b = bh >> 4;
  int q0 = qt * 64;
  int tid = threadIdx.x;
  int wave = tid >> 6, lane = tid & 63;
  int quad = lane >> 4, l16 = lane & 15;
  int qw = q0 + wave * 16;  // this wave's q rows [qw, qw+16)

  const __bf16* Qg = Q + ((size_t)(b * 2048 + qw + l16)) * 1024 + h * 64;
  bf16_8 qf0 = *(const bf16_8*)(Qg + quad * 8);
  bf16_8 qf1 = *(const bf16_8*)(Qg + 32 + quad * 8);

  f32x4 z = {0.f, 0.f, 0.f, 0.f};
  f32x4 o[4];  // o[dtile], rows in regs (C layout)
#pragma unroll
  for (int dt = 0; dt < 4; ++dt) o[dt] = z;
  float m_i[4] = {-1e30f, -1e30f, -1e30f, -1e30f};
  float l_i[4] = {0.f, 0.f, 0.f, 0.f};

  const __bf16* Kb = K + ((size_t)(b * 2048)) * 1024 + h * 64;
  const __bf16* Vb = V + ((size_t)(b * 2048)) * 1024 + h * 64;

  int ntiles = q0 / 32 + 2;  // keys [0, q0+64)
  for (int it = 0; it < ntiles; ++it) {
    int kt = it * 32;
    __syncthreads();  // protect K/V LDS reuse from previous iteration
    // --- stage K tile: wave w loads rows [w*8, w*8+8), 16B/lane ---
    gld_lds16(Kb + (size_t)(kt + wave * 8 + (lane >> 3)) * 1024 + (lane & 7) * 8,
              Kls + wave * 512);
    // --- stage V tile transposed: 256 threads x 8 elems ---
    {
      int s = tid >> 3;            // key 0..31
      int dc = (tid & 7) * 8;      // d chunk
      bf16_8 vv = *(const bf16_8*)(Vb + (size_t)(kt + s) * 1024 + dc);
#pragma unroll
      for (int j = 0; j < 8; ++j) Vls[(dc + j) * 32 + s] = vv[j];
    }
    __syncthreads();
    // --- S = Q K^T for two 16-key halves ---
    f32x4 sf[2];
#pragma unroll
    for (int half = 0; half < 2; ++half) {
      bf16_8 k0 = *(const bf16_8*)(Kls + (half * 16 + l16) * 64 + quad * 8);
      bf16_8 k1 = *(const bf16_8*)(Kls + (half * 16 + l16) * 64 + 32 + quad * 8);
      f32x4 a = z;
      a = __builtin_amdgcn_mfma_f32_16x16x32_bf16(qf0, k0, a, 0, 0, 0);
      a = __builtin_amdgcn_mfma_f32_16x16x32_bf16(qf1, k1, a, 0, 0, 0);
      sf[half] = a;
    }
    // --- online softmax per row (row m = quad*4+r; 16 cols across quad lanes)
#pragma unroll
    for (int r = 0; r < 4; ++r) {
      int qrow = qw + quad * 4 + r;
      float s0 = sf[0][r] * 0.03125f;
      float s1 = sf[1][r] * 0.03125f;
      if (kt + l16 > qrow) s0 = -1e30f;
      if (kt + 16 + l16 > qrow) s1 = -1e30f;
      float mx = fmaxf(s0, s1);
      mx = fmaxf(mx, __shfl_xor(mx, 1));
      mx = fmaxf(mx, __shfl_xor(mx, 2));
      mx = fmaxf(mx, __shfl_xor(mx, 4));
      mx = fmaxf(mx, __shfl_xor(mx, 8));
      float mnew = fmaxf(m_i[r], mx);
      float p0 = __expf(s0 - mnew);
      float p1 = __expf(s1 - mnew);
      float rsum = p0 + p1;
      rsum += __shfl_xor(rsum, 1);
      rsum += __shfl_xor(rsum, 2);
      rsum += __shfl_xor(rsum, 4);
      rsum += __shfl_xor(rsum, 8);
      float alpha = __expf(m_i[r] - mnew);
      l_i[r] = l_i[r] * alpha + rsum;
      m_i[r] = mnew;
      o[0][r] *= alpha; o[1][r] *= alpha; o[2][r] *= alpha; o[3][r] *= alpha;
      Pls[wave][(quad * 4 + r) * 32 + l16]      = (__bf16)p0;
      Pls[wave][(quad * 4 + r) * 32 + 16 + l16] = (__bf16)p1;
    }
    __syncthreads();  // P C-layout -> A-layout through LDS
    bf16_8 pf = *(const bf16_8*)(&Pls[wave][l16 * 32 + quad * 8]);
#pragma unroll
    for (int dt = 0; dt < 4; ++dt) {
      bf16_8 vf = *(const bf16_8*)(Vls + (dt * 16 + l16) * 32 + quad * 8);
      o[dt] = __builtin_amdgcn_mfma_f32_16x16x32_bf16(pf, vf, o[dt], 0, 0, 0);
    }
  }
  // --- epilogue: O / l, write bf16 [token][C] (concat heads) ---
#pragma unroll
  for (int r = 0; r < 4; ++r) {
    float inv = 1.0f / l_i[r];
    size_t row = (size_t)(b * 2048 + qw + quad * 4 + r) * 1024 + h * 64;
#pragma unroll
    for (int dt = 0; dt < 4; ++dt)
      O[row + dt * 16 + l16] = (__bf16)(o[dt][r] * inv);
  }
}

// ---------------------------------------------------------------------------
extern "C" void kernel_launch(void* const* d_in, const int* in_sizes, int n_in,
                              void* d_out, int out_size, void* d_ws,
                              size_t ws_size, hipStream_t stream) {
  const float* x   = (const float*)d_in[0];
  const float* Wq  = (const float*)d_in[1];
  const float* Wk  = (const float*)d_in[2];
  const float* Wv  = (const float*)d_in[3];
  const float* Wp  = (const float*)d_in[4];
  const float* bp  = (const float*)d_in[5];
  const float* W1  = (const float*)d_in[6];
  const float* b1  = (const float*)d_in[7];
  const float* W2  = (const float*)d_in[8];
  const float* b2  = (const float*)d_in[9];
  const float* l1w = (const float*)d_in[10];
  const float* l1b = (const float*)d_in[11];
  const float* l2w = (const float*)d_in[12];
  const float* l2b = (const float*)d_in[13];
  float* out = (float*)d_out;
  char* ws = (char*)d_ws;
  const size_t MB = 1024ull * 1024ull;
  // workspace layout (96 MB total)
  __bf16* WqT = (__bf16*)(ws + 0 * MB);   // 2 MB  [1024][1024]
  __bf16* WkT = (__bf16*)(ws + 2 * MB);   // 2 MB
  __bf16* WvT = (__bf16*)(ws + 4 * MB);   // 2 MB
  __bf16* WpT = (__bf16*)(ws + 6 * MB);   // 2 MB
  __bf16* W1T = (__bf16*)(ws + 8 * MB);   // 8 MB  [4096][1024]
  __bf16* W2T = (__bf16*)(ws + 16 * MB);  // 8 MB  [1024][4096]
  __bf16* hb  = (__bf16*)(ws + 24 * MB);  // 8 MB  LN out (reused for LN2)
  __bf16* Qb  = (__bf16*)(ws + 32 * MB);  // 8 MB
  __bf16* Kb  = (__bf16*)(ws + 40 * MB);  // 8 MB
  __bf16* Vb  = (__bf16*)(ws + 48 * MB);  // 8 MB
  __bf16* Ab  = (__bf16*)(ws + 56 * MB);  // 8 MB  attention out
  __bf16* F1  = (__bf16*)(ws + 64 * MB);  // 32 MB FFN hidden

  convt_k<<<12288, 256, 0, stream>>>(Wq, Wk, Wv, Wp, W1, W2,
                                     WqT, WkT, WvT, WpT, W1T, W2T);
  ln_k<<<4096, 256, 0, stream>>>(x, l1w, l1b, hb);
  // fused QKV: grid.y = chunk
  gemm_k<0><<<dim3(256, 3), 256, 0, stream>>>(hb, WqT, WkT, WvT, Qb, Kb, Vb,
                                              nullptr, nullptr, nullptr,
                                              1024, 1024, 8);
  attn_k<<<1024, 256, 0, stream>>>(Qb, Kb, Vb, Ab);
  // x1 = x + attn @ Wproj + bproj   (fp32, into d_out)
  gemm_k<2><<<dim3(256, 1), 256, 0, stream>>>(Ab, WpT, WpT, WpT, nullptr,
                                              nullptr, nullptr, out, bp, x,
                                              1024, 1024, 8);
  ln_k<<<4096, 256, 0, stream>>>(out, l2w, l2b, hb);
  // ff1 = relu(h2 @ W1 + b1)
  gemm_k<1><<<dim3(1024, 1), 256, 0, stream>>>(hb, W1T, W1T, W1T, F1, F1, F1,
                                               nullptr, b1, nullptr,
                                               1024, 4096, 32);
  // out = x1 + ff1 @ W2 + b2
  gemm_k<2><<<dim3(256, 1), 256, 0, stream>>>(F1, W2T, W2T, W2T, nullptr,
                                              nullptr, nullptr, out, b2, out,
                                              4096, 1024, 8);
}

// Round 2
// 433.602 us; speedup vs baseline: 1.2967x; 1.2967x over previous
//
#include <hip/hip_runtime.h>
#include <cstdint>

typedef __attribute__((ext_vector_type(8))) __bf16 bf16_8;
typedef __attribute__((ext_vector_type(4))) __bf16 bf16_4;
typedef __attribute__((ext_vector_type(4))) float f32x4;

// ---------------------------------------------------------------------------
// async global->LDS, 16B per lane. LDS dest = wave-uniform base + lane*16.
// Global source address may be arbitrary per-lane (we exploit this to build
// XOR-swizzled LDS images with zero extra cost).
// ---------------------------------------------------------------------------
__device__ __forceinline__ void gld_lds16(const __bf16* g, __bf16* l) {
  __builtin_amdgcn_global_load_lds(
      (const __attribute__((address_space(1))) void*)(void*)g,
      (__attribute__((address_space(3))) void*)l, 16, 0, 0);
}

// ---------------------------------------------------------------------------
// Fused weight transpose + f32->bf16 convert.  W[K][N] -> Wt[N][K] bf16.
// ---------------------------------------------------------------------------
__global__ __launch_bounds__(256) void convt_k(
    const float* __restrict__ Wq, const float* __restrict__ Wk,
    const float* __restrict__ Wv, const float* __restrict__ Wp,
    const float* __restrict__ W1, const float* __restrict__ W2,
    __bf16* __restrict__ WqT, __bf16* __restrict__ WkT,
    __bf16* __restrict__ WvT, __bf16* __restrict__ WpT,
    __bf16* __restrict__ W1T, __bf16* __restrict__ W2T) {
  int bid = blockIdx.x;
  const float* in; __bf16* outp; int Kd, Nd, tile;
  if (bid < 4096) {
    int m = bid >> 10; tile = bid & 1023; Kd = 1024; Nd = 1024;
    in   = m == 0 ? Wq  : m == 1 ? Wk  : m == 2 ? Wv  : Wp;
    outp = m == 0 ? WqT : m == 1 ? WkT : m == 2 ? WvT : WpT;
  } else if (bid < 8192) {
    tile = bid - 4096; Kd = 1024; Nd = 4096; in = W1; outp = W1T;
  } else {
    tile = bid - 8192; Kd = 4096; Nd = 1024; in = W2; outp = W2T;
  }
  int tilesN = Nd >> 5;
  int tk = tile / tilesN, tn = tile % tilesN;
  int k0 = tk * 32, n0 = tn * 32;
  __shared__ float tbuf[32][33];
  int tx = threadIdx.x & 31, ty = threadIdx.x >> 5;  // ty 0..7
#pragma unroll
  for (int i = 0; i < 4; ++i)
    tbuf[ty + i * 8][tx] = in[(size_t)(k0 + ty + i * 8) * Nd + (n0 + tx)];
  __syncthreads();
#pragma unroll
  for (int i = 0; i < 4; ++i)
    outp[(size_t)(n0 + ty + i * 8) * Kd + (k0 + tx)] = (__bf16)tbuf[tx][ty + i * 8];
}

// ---------------------------------------------------------------------------
// LayerNorm over rows of 1024, fp32 in -> bf16 out.  One block per row.
// ---------------------------------------------------------------------------
__global__ __launch_bounds__(256) void ln_k(const float* __restrict__ x,
                                            const float* __restrict__ w,
                                            const float* __restrict__ b,
                                            __bf16* __restrict__ out) {
  int row = blockIdx.x;
  const float* xr = x + (size_t)row * 1024;
  int tid = threadIdx.x;
  float v[4]; float s = 0.f, sq = 0.f;
#pragma unroll
  for (int i = 0; i < 4; ++i) {
    v[i] = xr[tid + i * 256]; s += v[i]; sq += v[i] * v[i];
  }
#pragma unroll
  for (int m = 1; m < 64; m <<= 1) { s += __shfl_xor(s, m); sq += __shfl_xor(sq, m); }
  __shared__ float rs[4], rq[4];
  int wave = tid >> 6, lane = tid & 63;
  if (lane == 0) { rs[wave] = s; rq[wave] = sq; }
  __syncthreads();
  s  = rs[0] + rs[1] + rs[2] + rs[3];
  sq = rq[0] + rq[1] + rq[2] + rq[3];
  float mu   = s * (1.f / 1024.f);
  float var  = sq * (1.f / 1024.f) - mu * mu;
  float rstd = rsqrtf(var + 1e-5f);
  __bf16* orow = out + (size_t)row * 1024;
#pragma unroll
  for (int i = 0; i < 4; ++i) {
    int c = tid + i * 256;
    orow[c] = (__bf16)((v[i] - mu) * rstd * w[c] + b[c]);
  }
}

// ---------------------------------------------------------------------------
// m97-style bf16 GEMM: C[M][N] = A[M][K] @ B[K][N], B given transposed
// Bt[N][K].  128x128 tile, BK=32, 4 waves each 64x64 (4x4 of 16x16x32 MFMA).
// MODE 0: bf16 out (per-chunk via blockIdx.y)
// MODE 1: bf16 out, +bias, ReLU
// MODE 2: f32  out, +bias, +f32 residual
// MODE 3: bf16 out written as V^T [b*16+h][64 d][2048 t]  (for attention)
// ---------------------------------------------------------------------------
template <int MODE>
__global__ __launch_bounds__(256) void gemm_k(
    const __bf16* __restrict__ A,
    const __bf16* __restrict__ B0, const __bf16* __restrict__ B1,
    const __bf16* __restrict__ B2,
    __bf16* __restrict__ O0, __bf16* __restrict__ O1, __bf16* __restrict__ O2,
    float* __restrict__ Of,
    const float* __restrict__ bias, const float* __restrict__ res,
    int K, int Nchunk, int nBlkN) {
  __shared__ __align__(16) __bf16 As[128 * 32];
  __shared__ __align__(16) __bf16 Bs[128 * 32];
  int chunk = blockIdx.y;
  const __bf16* Bt = chunk == 0 ? B0 : (chunk == 1 ? B1 : B2);
  __bf16* Ob       = chunk == 0 ? O0 : (chunk == 1 ? O1 : O2);
  int bm = blockIdx.x / nBlkN, bn = blockIdx.x % nBlkN;
  int m0 = bm * 128, n0 = bn * 128;
  int tid = threadIdx.x, wave = tid >> 6, lane = tid & 63;
  int quad = lane >> 4, l16 = lane & 15;
  int wm = (wave & 1) * 64, wn = (wave >> 1) * 64;

  f32x4 z = {0.f, 0.f, 0.f, 0.f};
  f32x4 acc[4][4];
#pragma unroll
  for (int mt = 0; mt < 4; ++mt)
#pragma unroll
    for (int nt = 0; nt < 4; ++nt) acc[mt][nt] = z;

  const __bf16* Ag = A  + (size_t)m0 * K;
  const __bf16* Bg = Bt + (size_t)n0 * K;
  int srow = lane >> 2;        // 16 rows per 1KB instruction
  int scol = (lane & 3) * 8;   // element offset within row

  for (int k0 = 0; k0 < K; k0 += 32) {
#pragma unroll
    for (int i = 0; i < 2; ++i) {
      int row = i * 64 + wave * 16 + srow;
      gld_lds16(Ag + (size_t)row * K + k0 + scol, As + (i * 64 + wave * 16) * 32);
      gld_lds16(Bg + (size_t)row * K + k0 + scol, Bs + (i * 64 + wave * 16) * 32);
    }
    __syncthreads();
    bf16_8 af[4], bfr[4];
#pragma unroll
    for (int t = 0; t < 4; ++t) {
      af[t]  = *(const bf16_8*)(As + (wm + t * 16 + l16) * 32 + quad * 8);
      bfr[t] = *(const bf16_8*)(Bs + (wn + t * 16 + l16) * 32 + quad * 8);
    }
#pragma unroll
    for (int mt = 0; mt < 4; ++mt)
#pragma unroll
      for (int nt = 0; nt < 4; ++nt)
        acc[mt][nt] = __builtin_amdgcn_mfma_f32_16x16x32_bf16(af[mt], bfr[nt],
                                                              acc[mt][nt], 0, 0, 0);
    __syncthreads();
  }

  if (MODE == 3) {
    // write V^T: element (m=token, n=h*64+d) -> Vt[(b*16+h)*64+d][2048] at t
    // 4 consecutive rows (r) = 4 consecutive tokens -> packed 8B store
#pragma unroll
    for (int mt = 0; mt < 4; ++mt) {
      int mbase = m0 + wm + mt * 16 + quad * 4;
      int bb = mbase >> 11, tt = mbase & 2047;
#pragma unroll
      for (int nt = 0; nt < 4; ++nt) {
        int n = n0 + wn + nt * 16 + l16;
        bf16_4 pk;
#pragma unroll
        for (int r = 0; r < 4; ++r) pk[r] = (__bf16)acc[mt][nt][r];
        *(bf16_4*)(O0 + ((size_t)((bb * 16 + (n >> 6)) * 64 + (n & 63))) * 2048 + tt) = pk;
      }
    }
    return;
  }

#pragma unroll
  for (int mt = 0; mt < 4; ++mt) {
#pragma unroll
    for (int r = 0; r < 4; ++r) {
      int m = m0 + wm + mt * 16 + quad * 4 + r;
      size_t rowo = (size_t)m * Nchunk;
#pragma unroll
      for (int nt = 0; nt < 4; ++nt) {
        int n = n0 + wn + nt * 16 + l16;
        float v = acc[mt][nt][r];
        if (MODE == 0) {
          Ob[rowo + n] = (__bf16)v;
        } else if (MODE == 1) {
          v += bias[n]; v = v > 0.f ? v : 0.f;
          Ob[rowo + n] = (__bf16)v;
        } else {
          v += bias[n] + res[rowo + n];
          Of[rowo + n] = v;
        }
      }
    }
  }
}

// ---------------------------------------------------------------------------
// Flash attention, causal, S^T/O^T formulation.
// Block = (b,h,64 q-rows); wave = 16 q-rows (col index l16 = q).
// 64-key tiles.  K and V^T staged via global_load_lds with XOR chunk swizzle
// ((lane&7)^(row&7)) so fragment b128 reads hit 8 bank-groups x 8 lanes.
// S^T = K.Q^T  (A = K rows, B = Q A-frag reused as Q^T B-frag)
//   -> per-lane softmax: row stats are lane scalars, 2 shuffles per reduce.
// O^T = V^T.P^T; P^T round-trips LDS per-wave (no barrier), stride 72.
// scale = C^-0.5 = 1/32 (reference scales by n_embd).
// ---------------------------------------------------------------------------
__global__ __launch_bounds__(256) void attn_k(const __bf16* __restrict__ Q,
                                              const __bf16* __restrict__ K,
                                              const __bf16* __restrict__ Vt,
                                              __bf16* __restrict__ O) {
  __shared__ __align__(16) __bf16 Kls[64 * 64];
  __shared__ __align__(16) __bf16 Vls[64 * 64];
  __shared__ __align__(16) __bf16 Pls[4][16 * 72];

  int blk = blockIdx.x;
  int qt = blk & 31, bh = blk >> 5;
  int h = bh & 15, b = bh >> 4;
  int q0 = qt * 64;
  int tid = threadIdx.x, wave = tid >> 6, lane = tid & 63;
  int quad = lane >> 4, l16 = lane & 15;
  int qw = q0 + wave * 16;
  int qrow = qw + l16;
  int r8 = lane >> 3, c8 = lane & 7;
  int cswz = c8 ^ r8;                    // staging chunk swizzle
  int so0 = (quad ^ (l16 & 7)) * 8;      // frag chunk offset, d/key chunk 0..3
  int so1 = so0 ^ 32;                    // chunk 4..7

  const __bf16* Qg = Q + ((size_t)(b * 2048 + qw + l16)) * 1024 + h * 64;
  bf16_8 qf0 = *(const bf16_8*)(Qg + quad * 8);        // Q[qrow][d 0..31]
  bf16_8 qf1 = *(const bf16_8*)(Qg + 32 + quad * 8);   // Q[qrow][d 32..63]

  const __bf16* Kb = K + (size_t)(b * 2048) * 1024 + h * 64;
  const __bf16* Vh = Vt + (size_t)((b * 16 + h) * 64) * 2048;

  f32x4 z = {0.f, 0.f, 0.f, 0.f};
  f32x4 ot[4];
#pragma unroll
  for (int dt = 0; dt < 4; ++dt) ot[dt] = z;
  float m_i = -1e30f, l_i = 0.f;
  __bf16* Pw = &Pls[wave][0];

  int ntiles = qt + 1;
  for (int it = 0; it < ntiles; ++it) {
    int kt = it * 64;
    __syncthreads();  // all waves done reading Kls/Vls from previous tile
#pragma unroll
    for (int i = 0; i < 2; ++i) {
      int rl = wave * 16 + i * 8 + r8;
      gld_lds16(Kb + (size_t)(kt + rl) * 1024 + cswz * 8,
                Kls + (wave * 16 + i * 8) * 64);
      gld_lds16(Vh + (size_t)rl * 2048 + kt + cswz * 8,
                Vls + (wave * 16 + i * 8) * 64);
    }
    __syncthreads();  // compiler drains vmcnt before barrier -> data visible

    // --- S^T = K . Q^T : sf[kk] rows = keys kk*16+quad*4+r, col = qrow ---
    f32x4 sf[4];
#pragma unroll
    for (int kk = 0; kk < 4; ++kk) {
      const __bf16* kr = Kls + (kk * 16 + l16) * 64;
      bf16_8 ka = *(const bf16_8*)(kr + so0);
      bf16_8 kb = *(const bf16_8*)(kr + so1);
      f32x4 a = z;
      a = __builtin_amdgcn_mfma_f32_16x16x32_bf16(ka, qf0, a, 0, 0, 0);
      a = __builtin_amdgcn_mfma_f32_16x16x32_bf16(kb, qf1, a, 0, 0, 0);
      sf[kk] = a;
    }

    // --- online softmax: all stats per-lane scalars ---
    float s[16];
    float mx = -1e30f;
#pragma unroll
    for (int kk = 0; kk < 4; ++kk)
#pragma unroll
      for (int r = 0; r < 4; ++r) {
        int key = kt + kk * 16 + quad * 4 + r;
        float v = sf[kk][r] * 0.03125f;
        v = (key > qrow) ? -1e30f : v;
        s[kk * 4 + r] = v;
        mx = fmaxf(mx, v);
      }
    mx = fmaxf(mx, __shfl_xor(mx, 16));
    mx = fmaxf(mx, __shfl_xor(mx, 32));
    float mnew = fmaxf(m_i, mx);
    float alpha = __expf(m_i - mnew);
    float rsum = 0.f;
#pragma unroll
    for (int kk = 0; kk < 4; ++kk) {
      bf16_4 pk;
#pragma unroll
      for (int r = 0; r < 4; ++r) {
        float p = __expf(s[kk * 4 + r] - mnew);
        rsum += p;
        pk[r] = (__bf16)p;
      }
      *(bf16_4*)(Pw + l16 * 72 + kk * 16 + quad * 4) = pk;  // P[qrow][key]
    }
    rsum += __shfl_xor(rsum, 16);
    rsum += __shfl_xor(rsum, 32);
    l_i = l_i * alpha + rsum;
    m_i = mnew;
#pragma unroll
    for (int dt = 0; dt < 4; ++dt) ot[dt] *= alpha;

    // --- O^T += V^T . P^T  (per-wave LDS round-trip, no barrier) ---
    bf16_8 pf0 = *(const bf16_8*)(Pw + l16 * 72 + quad * 8);        // keys 0..31
    bf16_8 pf1 = *(const bf16_8*)(Pw + l16 * 72 + 32 + quad * 8);   // keys 32..63
#pragma unroll
    for (int dt = 0; dt < 4; ++dt) {
      const __bf16* vr = Vls + (dt * 16 + l16) * 64;
      bf16_8 v0 = *(const bf16_8*)(vr + so0);
      bf16_8 v1 = *(const bf16_8*)(vr + so1);
      ot[dt] = __builtin_amdgcn_mfma_f32_16x16x32_bf16(v0, pf0, ot[dt], 0, 0, 0);
      ot[dt] = __builtin_amdgcn_mfma_f32_16x16x32_bf16(v1, pf1, ot[dt], 0, 0, 0);
    }
  }

  // --- epilogue: O^T holds O[qrow=l16][d=dt*16+quad*4+r]; scale by 1/l ---
  float inv = 1.0f / l_i;
  size_t base = (size_t)(b * 2048 + qw + l16) * 1024 + h * 64;
#pragma unroll
  for (int dt = 0; dt < 4; ++dt) {
    bf16_4 ok;
#pragma unroll
    for (int r = 0; r < 4; ++r) ok[r] = (__bf16)(ot[dt][r] * inv);
    *(bf16_4*)(O + base + dt * 16 + quad * 4) = ok;
  }
}

// ---------------------------------------------------------------------------
extern "C" void kernel_launch(void* const* d_in, const int* in_sizes, int n_in,
                              void* d_out, int out_size, void* d_ws,
                              size_t ws_size, hipStream_t stream) {
  const float* x   = (const float*)d_in[0];
  const float* Wq  = (const float*)d_in[1];
  const float* Wk  = (const float*)d_in[2];
  const float* Wv  = (const float*)d_in[3];
  const float* Wp  = (const float*)d_in[4];
  const float* bp  = (const float*)d_in[5];
  const float* W1  = (const float*)d_in[6];
  const float* b1  = (const float*)d_in[7];
  const float* W2  = (const float*)d_in[8];
  const float* b2  = (const float*)d_in[9];
  const float* l1w = (const float*)d_in[10];
  const float* l1b = (const float*)d_in[11];
  const float* l2w = (const float*)d_in[12];
  const float* l2b = (const float*)d_in[13];
  float* out = (float*)d_out;
  char* ws = (char*)d_ws;
  const size_t MB = 1024ull * 1024ull;
  __bf16* WqT = (__bf16*)(ws + 0 * MB);   // 2 MB  [1024][1024]
  __bf16* WkT = (__bf16*)(ws + 2 * MB);   // 2 MB
  __bf16* WvT = (__bf16*)(ws + 4 * MB);   // 2 MB
  __bf16* WpT = (__bf16*)(ws + 6 * MB);   // 2 MB
  __bf16* W1T = (__bf16*)(ws + 8 * MB);   // 8 MB  [4096][1024]
  __bf16* W2T = (__bf16*)(ws + 16 * MB);  // 8 MB  [1024][4096]
  __bf16* hb  = (__bf16*)(ws + 24 * MB);  // 8 MB  LN out (reused for LN2)
  __bf16* Qb  = (__bf16*)(ws + 32 * MB);  // 8 MB
  __bf16* Kb_ = (__bf16*)(ws + 40 * MB);  // 8 MB
  __bf16* Vt  = (__bf16*)(ws + 48 * MB);  // 8 MB  V^T [b*16+h][64][2048]
  __bf16* Ab  = (__bf16*)(ws + 56 * MB);  // 8 MB  attention out
  __bf16* F1  = (__bf16*)(ws + 64 * MB);  // 32 MB FFN hidden

  convt_k<<<12288, 256, 0, stream>>>(Wq, Wk, Wv, Wp, W1, W2,
                                     WqT, WkT, WvT, WpT, W1T, W2T);
  ln_k<<<4096, 256, 0, stream>>>(x, l1w, l1b, hb);
  // Q,K chunks (bf16 row-major out)
  gemm_k<0><<<dim3(256, 2), 256, 0, stream>>>(hb, WqT, WkT, WkT, Qb, Kb_, Kb_,
                                              nullptr, nullptr, nullptr,
                                              1024, 1024, 8);
  // V chunk written directly as V^T per head
  gemm_k<3><<<dim3(256, 1), 256, 0, stream>>>(hb, WvT, WvT, WvT, Vt, Vt, Vt,
                                              nullptr, nullptr, nullptr,
                                              1024, 1024, 8);
  attn_k<<<1024, 256, 0, stream>>>(Qb, Kb_, Vt, Ab);
  // x1 = x + attn @ Wproj + bproj   (fp32, into d_out)
  gemm_k<2><<<dim3(256, 1), 256, 0, stream>>>(Ab, WpT, WpT, WpT, nullptr,
                                              nullptr, nullptr, out, bp, x,
                                              1024, 1024, 8);
  ln_k<<<4096, 256, 0, stream>>>(out, l2w, l2b, hb);
  // ff1 = relu(h2 @ W1 + b1)
  gemm_k<1><<<dim3(1024, 1), 256, 0, stream>>>(hb, W1T, W1T, W1T, F1, F1, F1,
                                               nullptr, b1, nullptr,
                                               1024, 4096, 32);
  // out = x1 + ff1 @ W2 + b2
  gemm_k<2><<<dim3(256, 1), 256, 0, stream>>>(F1, W2T, W2T, W2T, nullptr,
                                              nullptr, nullptr, out, b2, out,
                                              4096, 1024, 8);
}

// Round 3
// 394.255 us; speedup vs baseline: 1.4261x; 1.0998x over previous
//
#include <hip/hip_runtime.h>
#include <cstdint>

typedef __attribute__((ext_vector_type(8))) __bf16 bf16_8;
typedef __attribute__((ext_vector_type(4))) __bf16 bf16_4;
typedef __attribute__((ext_vector_type(4))) float f32x4;

// ---------------------------------------------------------------------------
// async global->LDS, 16B per lane. LDS dest = wave-uniform base + lane*16.
// ---------------------------------------------------------------------------
__device__ __forceinline__ void gld_lds16(const __bf16* g, __bf16* l) {
  __builtin_amdgcn_global_load_lds(
      (const __attribute__((address_space(1))) void*)(void*)g,
      (__attribute__((address_space(3))) void*)l, 16, 0, 0);
}

// ---------------------------------------------------------------------------
// Fused weight transpose + f32->bf16 convert.  W[K][N] -> Wt[N][K] bf16.
// ---------------------------------------------------------------------------
__global__ __launch_bounds__(256) void convt_k(
    const float* __restrict__ Wq, const float* __restrict__ Wk,
    const float* __restrict__ Wv, const float* __restrict__ Wp,
    const float* __restrict__ W1, const float* __restrict__ W2,
    __bf16* __restrict__ WqT, __bf16* __restrict__ WkT,
    __bf16* __restrict__ WvT, __bf16* __restrict__ WpT,
    __bf16* __restrict__ W1T, __bf16* __restrict__ W2T) {
  int bid = blockIdx.x;
  const float* in; __bf16* outp; int Kd, Nd, tile;
  if (bid < 4096) {
    int m = bid >> 10; tile = bid & 1023; Kd = 1024; Nd = 1024;
    in   = m == 0 ? Wq  : m == 1 ? Wk  : m == 2 ? Wv  : Wp;
    outp = m == 0 ? WqT : m == 1 ? WkT : m == 2 ? WvT : WpT;
  } else if (bid < 8192) {
    tile = bid - 4096; Kd = 1024; Nd = 4096; in = W1; outp = W1T;
  } else {
    tile = bid - 8192; Kd = 4096; Nd = 1024; in = W2; outp = W2T;
  }
  int tilesN = Nd >> 5;
  int tk = tile / tilesN, tn = tile % tilesN;
  int k0 = tk * 32, n0 = tn * 32;
  __shared__ float tbuf[32][33];
  int tx = threadIdx.x & 31, ty = threadIdx.x >> 5;  // ty 0..7
#pragma unroll
  for (int i = 0; i < 4; ++i)
    tbuf[ty + i * 8][tx] = in[(size_t)(k0 + ty + i * 8) * Nd + (n0 + tx)];
  __syncthreads();
#pragma unroll
  for (int i = 0; i < 4; ++i)
    outp[(size_t)(n0 + ty + i * 8) * Kd + (k0 + tx)] = (__bf16)tbuf[tx][ty + i * 8];
}

// ---------------------------------------------------------------------------
// LayerNorm over rows of 1024, fp32 in -> bf16 out.  One block per row.
// ---------------------------------------------------------------------------
__global__ __launch_bounds__(256) void ln_k(const float* __restrict__ x,
                                            const float* __restrict__ w,
                                            const float* __restrict__ b,
                                            __bf16* __restrict__ out) {
  int row = blockIdx.x;
  int tid = threadIdx.x;
  f32x4 v = *(const f32x4*)(x + (size_t)row * 1024 + tid * 4);
  float s = v[0] + v[1] + v[2] + v[3];
  float sq = v[0] * v[0] + v[1] * v[1] + v[2] * v[2] + v[3] * v[3];
#pragma unroll
  for (int m = 1; m < 64; m <<= 1) { s += __shfl_xor(s, m); sq += __shfl_xor(sq, m); }
  __shared__ float rs[4], rq[4];
  int wave = tid >> 6, lane = tid & 63;
  if (lane == 0) { rs[wave] = s; rq[wave] = sq; }
  __syncthreads();
  s  = rs[0] + rs[1] + rs[2] + rs[3];
  sq = rq[0] + rq[1] + rq[2] + rq[3];
  float mu   = s * (1.f / 1024.f);
  float var  = sq * (1.f / 1024.f) - mu * mu;
  float rstd = rsqrtf(var + 1e-5f);
  f32x4 wv = *(const f32x4*)(w + tid * 4);
  f32x4 bv = *(const f32x4*)(b + tid * 4);
  bf16_4 o;
#pragma unroll
  for (int i = 0; i < 4; ++i) o[i] = (__bf16)((v[i] - mu) * rstd * wv[i] + bv[i]);
  *(bf16_4*)(out + (size_t)row * 1024 + tid * 4) = o;
}

// ---------------------------------------------------------------------------
// bf16 GEMM: C[M][N] = A[M][K] @ Bt^T, Bt[N][K].  Tile BMxBN, BK=32, 4 waves
// in 2x2, each (BM/2)x(BN/2) of 16x16x32 MFMA.  Grouped block swizzle
// (GROUP_M=8, bm fastest) for L2 locality.
// MODE 0: QKV fused via blockIdx.y; chunk 0/1 row-major bf16, chunk 2 writes
//         V^T [(b*16+h)*64+d][2048 tokens]
// MODE 1: bf16 out, +bias, ReLU
// MODE 2: f32  out, +bias, +f32 residual
// ---------------------------------------------------------------------------
template <int MODE, int BM, int BN>
__global__ __launch_bounds__(256) void gemm_k(
    const __bf16* __restrict__ A,
    const __bf16* __restrict__ B0, const __bf16* __restrict__ B1,
    const __bf16* __restrict__ B2,
    __bf16* __restrict__ O0, __bf16* __restrict__ O1, __bf16* __restrict__ O2,
    float* __restrict__ Of,
    const float* __restrict__ bias, const float* __restrict__ res,
    int K, int Nchunk, int nBlkM, int nBlkN) {
  constexpr int MT = BM / 32, NT = BN / 32;  // frags per wave
  __shared__ __align__(16) __bf16 As[BM * 32];
  __shared__ __align__(16) __bf16 Bs[BN * 32];
  int chunk = blockIdx.y;
  const __bf16* Bt = chunk == 0 ? B0 : (chunk == 1 ? B1 : B2);
  __bf16* Ob       = chunk == 0 ? O0 : (chunk == 1 ? O1 : O2);
  // grouped swizzle: consecutive blocks share a B-strip, span 8 A-strips
  int pid = blockIdx.x;
  const int GM = 8;
  int perG = GM * nBlkN;
  int gid = pid / perG;
  int fm = gid * GM;
  int gsz = min(nBlkM - fm, GM);
  int bm = fm + (pid % gsz);
  int bn = (pid % perG) / gsz;
  int m0 = bm * BM, n0 = bn * BN;
  int tid = threadIdx.x, wave = tid >> 6, lane = tid & 63;
  int quad = lane >> 4, l16 = lane & 15;
  int wm = (wave & 1) * (BM / 2), wn = (wave >> 1) * (BN / 2);

  f32x4 z = {0.f, 0.f, 0.f, 0.f};
  f32x4 acc[MT][NT];
#pragma unroll
  for (int mt = 0; mt < MT; ++mt)
#pragma unroll
    for (int nt = 0; nt < NT; ++nt) acc[mt][nt] = z;

  const __bf16* Ag = A  + (size_t)m0 * K;
  const __bf16* Bg = Bt + (size_t)n0 * K;
  int srow = lane >> 2;        // 16 rows per 1KB instruction
  int scol = (lane & 3) * 8;   // element offset within row

  for (int k0 = 0; k0 < K; k0 += 32) {
#pragma unroll
    for (int i = 0; i < BM / 64; ++i) {
      int row = i * 64 + wave * 16 + srow;
      gld_lds16(Ag + (size_t)row * K + k0 + scol, As + (i * 64 + wave * 16) * 32);
    }
#pragma unroll
    for (int i = 0; i < BN / 64; ++i) {
      int row = i * 64 + wave * 16 + srow;
      gld_lds16(Bg + (size_t)row * K + k0 + scol, Bs + (i * 64 + wave * 16) * 32);
    }
    __syncthreads();
    bf16_8 af[MT], bfr[NT];
#pragma unroll
    for (int t = 0; t < MT; ++t)
      af[t] = *(const bf16_8*)(As + (wm + t * 16 + l16) * 32 + quad * 8);
#pragma unroll
    for (int t = 0; t < NT; ++t)
      bfr[t] = *(const bf16_8*)(Bs + (wn + t * 16 + l16) * 32 + quad * 8);
#pragma unroll
    for (int mt = 0; mt < MT; ++mt)
#pragma unroll
      for (int nt = 0; nt < NT; ++nt)
        acc[mt][nt] = __builtin_amdgcn_mfma_f32_16x16x32_bf16(af[mt], bfr[nt],
                                                              acc[mt][nt], 0, 0, 0);
    __syncthreads();
  }

  if (MODE == 0 && chunk == 2) {
    // V^T write: (m=token, n=h*64+d) -> Vt[(b*16+h)*64+d][2048] at token
#pragma unroll
    for (int mt = 0; mt < MT; ++mt) {
      int mbase = m0 + wm + mt * 16 + quad * 4;
      int bb = mbase >> 11, tt = mbase & 2047;
#pragma unroll
      for (int nt = 0; nt < NT; ++nt) {
        int n = n0 + wn + nt * 16 + l16;
        bf16_4 pk;
#pragma unroll
        for (int r = 0; r < 4; ++r) pk[r] = (__bf16)acc[mt][nt][r];
        *(bf16_4*)(O2 + ((size_t)((bb * 16 + (n >> 6)) * 64 + (n & 63))) * 2048 + tt) = pk;
      }
    }
    return;
  }

#pragma unroll
  for (int mt = 0; mt < MT; ++mt) {
#pragma unroll
    for (int r = 0; r < 4; ++r) {
      int m = m0 + wm + mt * 16 + quad * 4 + r;
      size_t rowo = (size_t)m * Nchunk;
#pragma unroll
      for (int nt = 0; nt < NT; ++nt) {
        int n = n0 + wn + nt * 16 + l16;
        float v = acc[mt][nt][r];
        if (MODE == 0) {
          Ob[rowo + n] = (__bf16)v;
        } else if (MODE == 1) {
          v += bias[n]; v = v > 0.f ? v : 0.f;
          Ob[rowo + n] = (__bf16)v;
        } else {
          v += bias[n] + res[rowo + n];
          Of[rowo + n] = v;
        }
      }
    }
  }
}

// ---------------------------------------------------------------------------
// Flash attention, causal, S^T/O^T formulation (round-2 verified).
// ---------------------------------------------------------------------------
__global__ __launch_bounds__(256) void attn_k(const __bf16* __restrict__ Q,
                                              const __bf16* __restrict__ K,
                                              const __bf16* __restrict__ Vt,
                                              __bf16* __restrict__ O) {
  __shared__ __align__(16) __bf16 Kls[64 * 64];
  __shared__ __align__(16) __bf16 Vls[64 * 64];
  __shared__ __align__(16) __bf16 Pls[4][16 * 72];

  int blk = blockIdx.x;
  int qt = blk & 31, bh = blk >> 5;
  int h = bh & 15, b = bh >> 4;
  int q0 = qt * 64;
  int tid = threadIdx.x, wave = tid >> 6, lane = tid & 63;
  int quad = lane >> 4, l16 = lane & 15;
  int qw = q0 + wave * 16;
  int qrow = qw + l16;
  int r8 = lane >> 3, c8 = lane & 7;
  int cswz = c8 ^ r8;                    // staging chunk swizzle
  int so0 = (quad ^ (l16 & 7)) * 8;      // frag chunk offset
  int so1 = so0 ^ 32;

  const __bf16* Qg = Q + ((size_t)(b * 2048 + qw + l16)) * 1024 + h * 64;
  bf16_8 qf0 = *(const bf16_8*)(Qg + quad * 8);
  bf16_8 qf1 = *(const bf16_8*)(Qg + 32 + quad * 8);

  const __bf16* Kb = K + (size_t)(b * 2048) * 1024 + h * 64;
  const __bf16* Vh = Vt + (size_t)((b * 16 + h) * 64) * 2048;

  f32x4 z = {0.f, 0.f, 0.f, 0.f};
  f32x4 ot[4];
#pragma unroll
  for (int dt = 0; dt < 4; ++dt) ot[dt] = z;
  float m_i = -1e30f, l_i = 0.f;
  __bf16* Pw = &Pls[wave][0];

  int ntiles = qt + 1;
  for (int it = 0; it < ntiles; ++it) {
    int kt = it * 64;
    __syncthreads();
#pragma unroll
    for (int i = 0; i < 2; ++i) {
      int rl = wave * 16 + i * 8 + r8;
      gld_lds16(Kb + (size_t)(kt + rl) * 1024 + cswz * 8,
                Kls + (wave * 16 + i * 8) * 64);
      gld_lds16(Vh + (size_t)rl * 2048 + kt + cswz * 8,
                Vls + (wave * 16 + i * 8) * 64);
    }
    __syncthreads();

    f32x4 sf[4];
#pragma unroll
    for (int kk = 0; kk < 4; ++kk) {
      const __bf16* kr = Kls + (kk * 16 + l16) * 64;
      bf16_8 ka = *(const bf16_8*)(kr + so0);
      bf16_8 kb = *(const bf16_8*)(kr + so1);
      f32x4 a = z;
      a = __builtin_amdgcn_mfma_f32_16x16x32_bf16(ka, qf0, a, 0, 0, 0);
      a = __builtin_amdgcn_mfma_f32_16x16x32_bf16(kb, qf1, a, 0, 0, 0);
      sf[kk] = a;
    }

    float s[16];
    float mx = -1e30f;
#pragma unroll
    for (int kk = 0; kk < 4; ++kk)
#pragma unroll
      for (int r = 0; r < 4; ++r) {
        int key = kt + kk * 16 + quad * 4 + r;
        float v = sf[kk][r] * 0.03125f;
        v = (key > qrow) ? -1e30f : v;
        s[kk * 4 + r] = v;
        mx = fmaxf(mx, v);
      }
    mx = fmaxf(mx, __shfl_xor(mx, 16));
    mx = fmaxf(mx, __shfl_xor(mx, 32));
    float mnew = fmaxf(m_i, mx);
    float alpha = __expf(m_i - mnew);
    float rsum = 0.f;
#pragma unroll
    for (int kk = 0; kk < 4; ++kk) {
      bf16_4 pk;
#pragma unroll
      for (int r = 0; r < 4; ++r) {
        float p = __expf(s[kk * 4 + r] - mnew);
        rsum += p;
        pk[r] = (__bf16)p;
      }
      *(bf16_4*)(Pw + l16 * 72 + kk * 16 + quad * 4) = pk;
    }
    rsum += __shfl_xor(rsum, 16);
    rsum += __shfl_xor(rsum, 32);
    l_i = l_i * alpha + rsum;
    m_i = mnew;
#pragma unroll
    for (int dt = 0; dt < 4; ++dt) ot[dt] *= alpha;

    bf16_8 pf0 = *(const bf16_8*)(Pw + l16 * 72 + quad * 8);
    bf16_8 pf1 = *(const bf16_8*)(Pw + l16 * 72 + 32 + quad * 8);
#pragma unroll
    for (int dt = 0; dt < 4; ++dt) {
      const __bf16* vr = Vls + (dt * 16 + l16) * 64;
      bf16_8 v0 = *(const bf16_8*)(vr + so0);
      bf16_8 v1 = *(const bf16_8*)(vr + so1);
      ot[dt] = __builtin_amdgcn_mfma_f32_16x16x32_bf16(v0, pf0, ot[dt], 0, 0, 0);
      ot[dt] = __builtin_amdgcn_mfma_f32_16x16x32_bf16(v1, pf1, ot[dt], 0, 0, 0);
    }
  }

  float inv = 1.0f / l_i;
  size_t base = (size_t)(b * 2048 + qw + l16) * 1024 + h * 64;
#pragma unroll
  for (int dt = 0; dt < 4; ++dt) {
    bf16_4 ok;
#pragma unroll
    for (int r = 0; r < 4; ++r) ok[r] = (__bf16)(ot[dt][r] * inv);
    *(bf16_4*)(O + base + dt * 16 + quad * 4) = ok;
  }
}

// ---------------------------------------------------------------------------
extern "C" void kernel_launch(void* const* d_in, const int* in_sizes, int n_in,
                              void* d_out, int out_size, void* d_ws,
                              size_t ws_size, hipStream_t stream) {
  const float* x   = (const float*)d_in[0];
  const float* Wq  = (const float*)d_in[1];
  const float* Wk  = (const float*)d_in[2];
  const float* Wv  = (const float*)d_in[3];
  const float* Wp  = (const float*)d_in[4];
  const float* bp  = (const float*)d_in[5];
  const float* W1  = (const float*)d_in[6];
  const float* b1  = (const float*)d_in[7];
  const float* W2  = (const float*)d_in[8];
  const float* b2  = (const float*)d_in[9];
  const float* l1w = (const float*)d_in[10];
  const float* l1b = (const float*)d_in[11];
  const float* l2w = (const float*)d_in[12];
  const float* l2b = (const float*)d_in[13];
  float* out = (float*)d_out;
  char* ws = (char*)d_ws;
  const size_t MB = 1024ull * 1024ull;
  __bf16* WqT = (__bf16*)(ws + 0 * MB);   // 2 MB  [1024][1024]
  __bf16* WkT = (__bf16*)(ws + 2 * MB);   // 2 MB
  __bf16* WvT = (__bf16*)(ws + 4 * MB);   // 2 MB
  __bf16* WpT = (__bf16*)(ws + 6 * MB);   // 2 MB
  __bf16* W1T = (__bf16*)(ws + 8 * MB);   // 8 MB  [4096][1024]
  __bf16* W2T = (__bf16*)(ws + 16 * MB);  // 8 MB  [1024][4096]
  __bf16* hb  = (__bf16*)(ws + 24 * MB);  // 8 MB  LN out (reused for LN2)
  __bf16* Qb  = (__bf16*)(ws + 32 * MB);  // 8 MB
  __bf16* Kb_ = (__bf16*)(ws + 40 * MB);  // 8 MB
  __bf16* Vt  = (__bf16*)(ws + 48 * MB);  // 8 MB  V^T [b*16+h][64][2048]
  __bf16* Ab  = (__bf16*)(ws + 56 * MB);  // 8 MB  attention out
  __bf16* F1  = (__bf16*)(ws + 64 * MB);  // 32 MB FFN hidden

  convt_k<<<12288, 256, 0, stream>>>(Wq, Wk, Wv, Wp, W1, W2,
                                     WqT, WkT, WvT, WpT, W1T, W2T);
  ln_k<<<4096, 256, 0, stream>>>(x, l1w, l1b, hb);
  // fused QKV (chunk 2 writes V^T per head)
  gemm_k<0, 128, 128><<<dim3(256, 3), 256, 0, stream>>>(
      hb, WqT, WkT, WvT, Qb, Kb_, Vt, nullptr, nullptr, nullptr,
      1024, 1024, 32, 8);
  attn_k<<<1024, 256, 0, stream>>>(Qb, Kb_, Vt, Ab);
  // x1 = x + attn @ Wproj + bproj   (fp32, into d_out); 128x64 tiles
  gemm_k<2, 128, 64><<<dim3(512, 1), 256, 0, stream>>>(
      Ab, WpT, WpT, WpT, nullptr, nullptr, nullptr, out, bp, x,
      1024, 1024, 32, 16);
  ln_k<<<4096, 256, 0, stream>>>(out, l2w, l2b, hb);
  // ff1 = relu(h2 @ W1 + b1)
  gemm_k<1, 128, 128><<<dim3(1024, 1), 256, 0, stream>>>(
      hb, W1T, W1T, W1T, F1, F1, F1, nullptr, b1, nullptr,
      1024, 4096, 32, 32);
  // out = x1 + ff1 @ W2 + b2 ; 128x64 tiles
  gemm_k<2, 128, 64><<<dim3(512, 1), 256, 0, stream>>>(
      F1, W2T, W2T, W2T, nullptr, nullptr, nullptr, out, b2, out,
      4096, 1024, 32, 16);
}